// Round 1
// 424.185 us; speedup vs baseline: 1.0329x; 1.0329x over previous
//
#include <hip/hip_runtime.h>
#include <hip/hip_bf16.h>

// Problem constants
#define B_   8
#define CIN  64
#define CM   16      // compressed channels
#define H_   192
#define W_   384
#define ND   41      // MAX_DISP+1
#define HW   (H_ * W_)
#define SLOPE 0.1f
#define SMINI ((size_t)B_ * CM * H_ * W_)   // elems per compressed tensor

typedef __attribute__((ext_vector_type(8))) short short8v;   // 8 bf16 = 1 MFMA frag
typedef __attribute__((ext_vector_type(4))) float floatx4;

__device__ __forceinline__ float bf2f(short h) {
    union { unsigned u; float f; } cv;
    cv.u = ((unsigned)(unsigned short)h) << 16;
    return cv.f;
}
__device__ __forceinline__ short f2bf(float f) {
    __hip_bfloat16 h = __float2bfloat16(f);   // RNE
    return *(short*)&h;
}

// ---------------------------------------------------------------------------
// Kernel 0: reorder weights OIHW fp32 -> [co][k] bf16 with k = (dy*3+dx)*64 + c
// ---------------------------------------------------------------------------
__global__ void wprep_kernel(const float* __restrict__ w, short* __restrict__ wbf) {
    int i = blockIdx.x * 256 + threadIdx.x;
    if (i >= CM * 576) return;
    int co = i / 576, k = i - co * 576;
    int t = k >> 6, c = k & 63;               // k = t*64 + c
    wbf[i] = f2bf(w[(co * CIN + c) * 9 + t]); // w[co][c][dy][dx], t = dy*3+dx
}

// ---------------------------------------------------------------------------
// Kernel 1: 3x3 conv 64->16 + bias + LeakyReLU via MFMA implicit GEMM.
// Block: 6x32 output pixels of one (tensor,b). LDS: 8x34 input sites x 64c bf16
// [site][c] stride 72 (2-way bank alias = free). A-operand = weights (16 co as
// M), B-operand = pixels (N). D lane layout -> contiguous [pixel][co] bf16 NHWC
// stores, 8 B/lane fully coalesced.
//
// Staging is software-pipelined: phase 1 issues ALL 20 aligned float4 loads per
// thread into a register array (keeps ~20 VMEM ops in flight instead of the
// previous serialized 17 round-trips at 56 VGPRs); phase 2 converts fp32->bf16
// and writes LDS. x-window is rounded to [x0-4, x0+36) so every global load is
// an exact 16B-aligned dwordx4 (no partial-cacheline overfetch).
// ---------------------------------------------------------------------------
#define YT 6
#define XT 32
#define LC 34
#define PSTR 72

__global__ __launch_bounds__(256, 4) void conv_mfma(
    const float* __restrict__ ina, const float* __restrict__ inb,
    const short* __restrict__ wbf, const float* __restrict__ bias,
    short* __restrict__ mini)      // [2][B][H][W][16] bf16
{
    __shared__ __align__(16) short px[8 * LC * PSTR];   // 39,168 B

    int blk = blockIdx.x;
    int xt = blk % 12;  blk /= 12;
    int yt = blk % 32;  blk /= 32;
    int b  = blk & 7;
    int t  = blk >> 3;
    const float* src = t ? inb : ina;
    int x0 = xt * XT, y0 = yt * YT;
    int tid = threadIdx.x;

    // ---- phase 1: issue all staged loads -----------------------------------
    // tasks: 8 rows x 16 c-quads x 10 x-quads = 1280 = 5 * 256
    // x-quad xq covers global x = x0-4+4*xq .. +3 (16B aligned; W%4==0 so each
    // float4 is entirely in or out of bounds).
    floatx4 v[5][4];          // [task][channel 0..3] of 4 x-pixels
    int wbase_[5], lxb_[5];
    #pragma unroll
    for (int i = 0; i < 5; ++i) {
        int e = i * 256 + tid;     // 0..1279
        int xq = e % 10;
        int rcq = e / 10;          // 0..127
        int row = rcq >> 4;        // 0..7
        int c0 = (rcq & 15) << 2;  // 0,4,..,60
        int gy = y0 - 1 + row;
        int gx = x0 - 4 + xq * 4;  // -4 .. x0+36
        int lxb = gx - x0 + 1;     // LDS x of element j=0 (may be <0 / >=LC)
        lxb_[i] = lxb;
        wbase_[i] = (row * LC + lxb) * PSTR + c0;
        floatx4 z4 = {0.f, 0.f, 0.f, 0.f};
        floatx4 a0 = z4, a1 = z4, a2 = z4, a3 = z4;
        if ((unsigned)gy < (unsigned)H_ && (unsigned)gx < (unsigned)W_) {
            const float* p = src + (size_t)(b * CIN + c0) * HW
                           + (size_t)gy * W_ + gx;
            a0 = *(const floatx4*)p;
            a1 = *(const floatx4*)(p + HW);
            a2 = *(const floatx4*)(p + 2 * HW);
            a3 = *(const floatx4*)(p + 3 * HW);
        }
        v[i][0] = a0; v[i][1] = a1; v[i][2] = a2; v[i][3] = a3;
    }

    // ---- phase 2: convert + LDS transpose-write ----------------------------
    #pragma unroll
    for (int i = 0; i < 5; ++i) {
        #pragma unroll
        for (int j = 0; j < 4; ++j) {
            if ((unsigned)(lxb_[i] + j) < (unsigned)LC) {
                short4 q;
                q.x = f2bf(v[i][0][j]);
                q.y = f2bf(v[i][1][j]);
                q.z = f2bf(v[i][2][j]);
                q.w = f2bf(v[i][3][j]);
                *(short4*)(px + wbase_[i] + j * PSTR) = q;   // 8 B, aligned
            }
        }
    }

    int lane = tid & 63;
    int n16  = lane & 15;    // A: co row group ; B/D: pixel within tile
    int quad = lane >> 4;

    // ---- preload weight A-frags for all 18 K-steps (L1/L2-hot, 18 KB) ----
    // placed after staging so the 72 weight VGPRs don't overlap the 80
    // staging VGPRs; latency hides under other waves / the barrier.
    short8v af[18];
    #pragma unroll
    for (int ks = 0; ks < 18; ++ks)
        af[ks] = *(const short8v*)(wbf + n16 * 576 + ks * 32 + quad * 8);

    __syncthreads();

    // ---- MFMA main loop: 3 M-tiles per wave, 18 K-steps ----
    int wv = tid >> 6;
    floatx4 acc[3] = {{0,0,0,0},{0,0,0,0},{0,0,0,0}};
    int base[3];
    #pragma unroll
    for (int j = 0; j < 3; ++j) {
        int mt = wv * 3 + j;                 // 0..11
        int r = mt >> 1, xb = (mt & 1) << 4; // output row 0..5, x-base 0/16
        base[j] = (r * LC + xb + n16) * PSTR + quad * 8;
    }
    #pragma unroll
    for (int ks = 0; ks < 18; ++ks) {
        const int tap = ks >> 1, ch = ks & 1;
        const int dy = tap / 3, dx = tap % 3;
        const int off = (dy * LC + dx) * PSTR + ch * 32;   // compile-time
        #pragma unroll
        for (int j = 0; j < 3; ++j) {
            short8v bfr = *(const short8v*)(px + base[j] + off);
            acc[j] = __builtin_amdgcn_mfma_f32_16x16x32_bf16(af[ks], bfr, acc[j], 0, 0, 0);
        }
    }

    // ---- epilogue: bias + LeakyReLU, bf16 NHWC store (8 B/lane coalesced) ----
    float bia[4];
    #pragma unroll
    for (int i = 0; i < 4; ++i) bia[i] = bias[quad * 4 + i];
    #pragma unroll
    for (int j = 0; j < 3; ++j) {
        int mt = wv * 3 + j;
        int r = mt >> 1, xb = (mt & 1) << 4;
        int y = y0 + r, x = x0 + xb + n16;
        size_t o = (((size_t)(t * B_ + b) * H_ + y) * W_ + x) * CM + quad * 4;
        short4 q;
        float v2;
        v2 = acc[j][0] + bia[0]; v2 = v2 >= 0.f ? v2 : SLOPE * v2; q.x = f2bf(v2);
        v2 = acc[j][1] + bia[1]; v2 = v2 >= 0.f ? v2 : SLOPE * v2; q.y = f2bf(v2);
        v2 = acc[j][2] + bia[2]; v2 = v2 >= 0.f ? v2 : SLOPE * v2; q.z = f2bf(v2);
        v2 = acc[j][3] + bia[3]; v2 = v2 >= 0.f ? v2 : SLOPE * v2; q.w = f2bf(v2);
        *(short4*)(mini + o) = q;
    }
}

// ---------------------------------------------------------------------------
// Kernel 2: 41-disparity correlation over NHWC bf16 mini. One block per (b,y).
// b-row staged in LDS at 48 B/pixel stride (16 B aligned, 2-way alias = free).
// ---------------------------------------------------------------------------
#define BSTR 24   // shorts per pixel in LDS (16 data + 8 pad)

__global__ __launch_bounds__(384) void corr_nhwc(
    const short* __restrict__ mini, float* __restrict__ out)
{
    __shared__ __align__(16) short bl[W_ * BSTR];   // 18,432 B
    int b = blockIdx.x / H_;
    int y = blockIdx.x % H_;
    int x = threadIdx.x;   // 0..383

    size_t arow = ((size_t)b * H_ + y) * W_ * CM;          // tensor 0
    size_t brow = ((size_t)(B_ + b) * H_ + y) * W_ * CM;   // tensor 1

    short8v p0 = *(const short8v*)(mini + brow + (size_t)x * CM);
    short8v p1 = *(const short8v*)(mini + brow + (size_t)x * CM + 8);
    *(short8v*)(bl + x * BSTR) = p0;
    *(short8v*)(bl + x * BSTR + 8) = p1;

    float av[16];
    short8v a0 = *(const short8v*)(mini + arow + (size_t)x * CM);
    short8v a1 = *(const short8v*)(mini + arow + (size_t)x * CM + 8);
    #pragma unroll
    for (int i = 0; i < 8; ++i) { av[i] = bf2f(a0[i]); av[8 + i] = bf2f(a1[i]); }

    __syncthreads();

    float* ob = out + ((size_t)b * ND * H_ + y) * W_ + x;
    #pragma unroll 1
    for (int d = 0; d < ND; ++d) {
        float s = 0.f;
        int xs = x - d;
        if (xs >= 0) {
            const short* bp = bl + xs * BSTR;
            short8v c0 = *(const short8v*)bp;
            short8v c1 = *(const short8v*)(bp + 8);
            float s0 = 0.f, s1 = 0.f;
            #pragma unroll
            for (int i = 0; i < 8; ++i) {
                s0 += av[i]     * bf2f(c0[i]);
                s1 += av[8 + i] * bf2f(c1[i]);
            }
            s = s0 + s1;
        }
        ob[(size_t)d * HW] = s * 0.0625f;
    }
}

// ---------------------------------------------------------------------------
extern "C" void kernel_launch(void* const* d_in, const int* in_sizes, int n_in,
                              void* d_out, int out_size, void* d_ws, size_t ws_size,
                              hipStream_t stream) {
    const float* conv1a = (const float*)d_in[0];
    const float* conv1b = (const float*)d_in[1];
    const float* W_comp = (const float*)d_in[2];
    const float* b_comp = (const float*)d_in[3];
    float* out = (float*)d_out;

    short* mini = (short*)d_ws;            // 2*SMINI bf16 = 37.7 MB
    short* wbf  = mini + 2 * SMINI;        // 16x576 bf16

    wprep_kernel<<<36, 256, 0, stream>>>(W_comp, wbf);
    conv_mfma<<<2 * B_ * 32 * 12, 256, 0, stream>>>(conv1a, conv1b, wbf, b_comp, mini);
    corr_nhwc<<<B_ * H_, 384, 0, stream>>>(mini, out);
}